// Round 3
// baseline (892.394 us; speedup 1.0000x reference)
//
#include <hip/hip_runtime.h>
#include <stdint.h>

#define NN 8192
#define DD 128

typedef __attribute__((ext_vector_type(4))) float floatx4;
typedef __attribute__((ext_vector_type(8))) short s16x8;
typedef __attribute__((ext_vector_type(8))) unsigned short u16x8;
typedef __attribute__((ext_vector_type(4))) unsigned short u16x4;

__device__ inline unsigned short f32_bf16(float f) {
    union { float f; uint32_t u; } v; v.f = f;
    uint32_t u = v.u;
    return (unsigned short)((u + 0x7FFFu + ((u >> 16) & 1u)) >> 16);
}

// ---------------------------------------------------------------------------
// convert_adj: adj fp32 [8192][8192] -> dstN bf16 [r][c], dstT bf16 [c][r],
// rsum[r] (+= fp32 row sums), csum[c] (+= fp32 col sums).
// Tile 256x256, 512 threads (8 waves). Every global access is >=512B
// contiguous per wave instruction. LDS transpose staging uses XOR-swizzled
// 4-short granules: both write and read phases sit at the bank floor.
// ---------------------------------------------------------------------------
__global__ __launch_bounds__(512) void convert_adj(const float* __restrict__ src,
        unsigned short* __restrict__ dstT, unsigned short* __restrict__ dstN,
        float* __restrict__ rsum, float* __restrict__ csum) {
    __shared__ __align__(16) unsigned short LT[256 * 256]; // swizzled [c][r-granule]
    __shared__ float colacc[256];
    int r0 = blockIdx.x * 256, c0 = blockIdx.y * 256;
    int t = threadIdx.x;
    int w = t >> 6, l = t & 63;
    if (t < 256) colacc[t] = 0.f;
    __syncthreads();

    float ca0 = 0.f, ca1 = 0.f, ca2 = 0.f, ca3 = 0.f;
    // wave w handles rows g*32 + w*4 + i  (g=0..7, i=0..3): 4 consecutive rows
    // per group so the transpose granule [c][r..r+3] lives in one lane.
    for (int g = 0; g < 8; ++g) {
        unsigned short q[4][4];
#pragma unroll
        for (int i = 0; i < 4; ++i) {
            int r = g * 32 + w * 4 + i;
            floatx4 f = *(const floatx4*)(src + (size_t)(r0 + r) * NN + c0 + 4 * l);
            u16x4 pk;
#pragma unroll
            for (int j = 0; j < 4; ++j) { pk[j] = f32_bf16(f[j]); q[i][j] = pk[j]; }
            *(u16x4*)(dstN + (size_t)(r0 + r) * NN + c0 + 4 * l) = pk;
            // row sum: full-wave reduce (256 cols)
            float s = (f[0] + f[1]) + (f[2] + f[3]);
            s += __shfl_xor(s, 1);  s += __shfl_xor(s, 2);  s += __shfl_xor(s, 4);
            s += __shfl_xor(s, 8);  s += __shfl_xor(s, 16); s += __shfl_xor(s, 32);
            if (l == 0) atomicAdd(&rsum[r0 + r], s);
            ca0 += f[0]; ca1 += f[1]; ca2 += f[2]; ca3 += f[3];
        }
        // transpose granule write: col c = 4l+j, r-quad rq = g*8+w
        int rq = g * 8 + w;
#pragma unroll
        for (int j = 0; j < 4; ++j) {
            int c = 4 * l + j;
            u16x4 gr;
#pragma unroll
            for (int i = 0; i < 4; ++i) gr[i] = q[i][j];
            *(u16x4*)(&LT[c * 256 + 4 * (rq ^ (l & 15))]) = gr;
        }
    }
    atomicAdd(&colacc[4 * l + 0], ca0);
    atomicAdd(&colacc[4 * l + 1], ca1);
    atomicAdd(&colacc[4 * l + 2], ca2);
    atomicAdd(&colacc[4 * l + 3], ca3);
    __syncthreads();
    if (t < 256) atomicAdd(&csum[c0 + t], colacc[t]);
    // dstT write-out: wave w handles cols w*32..w*32+31; lane l reads granule l
#pragma unroll 4
    for (int cc = 0; cc < 32; ++cc) {
        int c = w * 32 + cc;
        u16x4 d = *(const u16x4*)(&LT[c * 256 + 4 * (l ^ ((c >> 2) & 15))]);
        *(u16x4*)(dstT + (size_t)(c0 + c) * NN + r0 + 4 * l) = d;
    }
}

// ---------------------------------------------------------------------------
// convert_feat: src fp32 [R][C] -> dstT bf16 [C][R] (features only).
// Tile 64x64, block=256 (validated in R1/R2).
// ---------------------------------------------------------------------------
__global__ __launch_bounds__(256) void convert_feat(const float* __restrict__ src,
        unsigned short* __restrict__ dstT, int R, int C) {
    __shared__ __align__(16) unsigned short lt[64 * 68];
    int r0 = blockIdx.x * 64, c0 = blockIdx.y * 64;
    int t = threadIdx.x, tx = t & 15, ty = t >> 4;
    const float* sp = src + (size_t)(r0 + ty * 4) * C + c0 + tx * 4;
    float f[4][4];
#pragma unroll
    for (int i = 0; i < 4; ++i) {
        floatx4 v = *(const floatx4*)(sp + (size_t)i * C);
        f[i][0] = v[0]; f[i][1] = v[1]; f[i][2] = v[2]; f[i][3] = v[3];
    }
#pragma unroll
    for (int j = 0; j < 4; ++j) {
        u16x4 pk;
#pragma unroll
        for (int i = 0; i < 4; ++i) pk[i] = f32_bf16(f[i][j]);
        *(u16x4*)(&lt[(tx * 4 + j) * 68 + ty * 4]) = pk;
    }
    __syncthreads();
    int cc = t >> 2, seg = t & 3;
    u16x4 q0 = *(const u16x4*)(&lt[cc * 68 + seg * 16]);
    u16x4 q1 = *(const u16x4*)(&lt[cc * 68 + seg * 16 + 4]);
    u16x4 q2 = *(const u16x4*)(&lt[cc * 68 + seg * 16 + 8]);
    u16x4 q3 = *(const u16x4*)(&lt[cc * 68 + seg * 16 + 12]);
    u16x8 o0, o1;
#pragma unroll
    for (int e = 0; e < 4; ++e) { o0[e] = q0[e]; o0[4 + e] = q1[e];
                                  o1[e] = q2[e]; o1[4 + e] = q3[e]; }
    unsigned short* dp = dstT + (size_t)(c0 + cc) * R + r0 + seg * 16;
    *(u16x8*)dp = o0;
    *(u16x8*)(dp + 8) = o1;
}

// ---------------------------------------------------------------------------
// gemm_bigK: Yt[slice][n][m] = A[m, kslice] @ B[kslice, n]   (fp32 out)
//   A bf16 row-major [m][k] (ld=NN), B bf16 transposed Bt[n=128][k=NN].
// BM=128, BK=256 (rows = 512B contiguous reads), 512 threads = 8 waves (4x2),
// split-K = 8 (blockIdx.y), k-loop = 4 iters, register prefetch.
// LDS stride 264 shorts: all b128 LDS ops at the 8-phase bank floor.
// ---------------------------------------------------------------------------
__global__ __launch_bounds__(512, 2) void gemm_bigK(
        const unsigned short* __restrict__ A16,
        const unsigned short* __restrict__ Bt, float* __restrict__ Yt) {
    __shared__ __align__(16) unsigned short LA[128 * 264];
    __shared__ __align__(16) unsigned short LB[128 * 264];
    int m0 = blockIdx.x * 128;
    int kbase = blockIdx.y * (NN / 8);
    int t = threadIdx.x;
    int w = t >> 6, l = t & 63;
    int wy = w >> 1, wx = w & 1;           // 4x2 wave grid: 32m x 64n per wave
    int l15 = l & 15, l4 = l >> 4;
    // staging map: per j: row = w*16 + (l>>5)*8 + j, k-seg = (l&31)*8 shorts
    int srow = w * 16 + (l >> 5) * 8;
    int skk = (l & 31) * 8;
    const unsigned short* ap = A16 + (size_t)(m0 + srow) * NN + kbase + skk;
    const unsigned short* bp = Bt + (size_t)srow * NN + kbase + skk;

    floatx4 acc[2][4] = {};
    u16x8 ra[8], rb[8];
#pragma unroll
    for (int j = 0; j < 8; ++j) {
        ra[j] = *(const u16x8*)(ap + (size_t)j * NN);
        rb[j] = *(const u16x8*)(bp + (size_t)j * NN);
    }
    for (int kt = 0; kt < 4; ++kt) {
#pragma unroll
        for (int j = 0; j < 8; ++j) {
            *(u16x8*)(&LA[(srow + j) * 264 + skk]) = ra[j];
            *(u16x8*)(&LB[(srow + j) * 264 + skk]) = rb[j];
        }
        __syncthreads();
        if (kt < 3) {
            int off = (kt + 1) * 256;
#pragma unroll
            for (int j = 0; j < 8; ++j) {
                ra[j] = *(const u16x8*)(ap + (size_t)j * NN + off);
                rb[j] = *(const u16x8*)(bp + (size_t)j * NN + off);
            }
        }
#pragma unroll
        for (int ks = 0; ks < 8; ++ks) {
            s16x8 af[2], bf[4];
#pragma unroll
            for (int i = 0; i < 2; ++i)
                af[i] = *(const s16x8*)(&LA[(wy * 32 + i * 16 + l15) * 264 + ks * 32 + l4 * 8]);
#pragma unroll
            for (int j = 0; j < 4; ++j)
                bf[j] = *(const s16x8*)(&LB[(wx * 64 + j * 16 + l15) * 264 + ks * 32 + l4 * 8]);
#pragma unroll
            for (int i = 0; i < 2; ++i)
#pragma unroll
                for (int j = 0; j < 4; ++j)
                    acc[i][j] = __builtin_amdgcn_mfma_f32_16x16x32_bf16(
                        af[i], bf[j], acc[i][j], 0, 0, 0);
        }
        __syncthreads();
    }
    // C write: Yt[slice][col][m], m-contiguous dwordx4 (acc f4 = 4 consecutive m)
    float* Y = Yt + (size_t)blockIdx.y * ((size_t)DD * NN);
#pragma unroll
    for (int i = 0; i < 2; ++i)
#pragma unroll
        for (int j = 0; j < 4; ++j) {
            int col = wx * 64 + j * 16 + l15;
            int m = m0 + wy * 32 + i * 16 + l4 * 4;
            *(floatx4*)(Y + (size_t)col * NN + m) = acc[i][j];
        }
}

// ---------------------------------------------------------------------------
// gemm_smallV: Z[m][f] = (sum_s Yt[s][:][m]) @ W * (1/sums[m])   (VALU fp32)
//   Yt fp32 [8][128 n][8192 m]; W fp32 [128 n][128 f] (no bf16 rounding).
//   out32 fp32 [8192][128] and/or outT bf16 [128 f][8192 m].
// BM=32, grid 256, block=256.
// ---------------------------------------------------------------------------
__global__ __launch_bounds__(256) void gemm_smallV(const float* __restrict__ Yt,
        const float* __restrict__ W, const float* __restrict__ sums,
        float* __restrict__ out32, unsigned short* __restrict__ outT) {
    __shared__ float Ys[128][36];    // [n][m] m-contiguous
    __shared__ float Wl[128][132];   // [n][f]
    int m0 = blockIdx.x * 32;
    int t = threadIdx.x;
    {   // load W: 2 threads per n-row, 64 f each
        int n = t >> 1, fs = (t & 1) * 64;
#pragma unroll
        for (int i = 0; i < 16; ++i)
            *(floatx4*)(&Wl[n][fs + 4 * i]) = *(const floatx4*)(W + n * DD + fs + 4 * i);
    }
    {   // slice-sum: cell (n, m-quad): lanes cover 8 m-quads x 8 n per wave
        int mq = t & 7, n8 = t >> 3;
#pragma unroll
        for (int g = 0; g < 4; ++g) {
            int n = g * 32 + n8;
            const float* yp = Yt + (size_t)n * NN + m0 + mq * 4;
            floatx4 s = {0.f, 0.f, 0.f, 0.f};
#pragma unroll
            for (int sl = 0; sl < 8; ++sl)
                s += *(const floatx4*)(yp + (size_t)sl * ((size_t)DD * NN));
            *(floatx4*)(&Ys[n][mq * 4]) = s;
        }
    }
    __syncthreads();
    // outputs: thread owns (m = t>>3, f = 4*(t&7) + 32q + e)
    int m = t >> 3, fb = (t & 7) * 4;
    float inv = 1.0f / sums[m0 + m];
    floatx4 acc[4] = {};
    for (int n = 0; n < 128; ++n) {
        float a = Ys[n][m];
#pragma unroll
        for (int q = 0; q < 4; ++q) {
            floatx4 wv = *(const floatx4*)(&Wl[n][fb + 32 * q]);
            acc[q] += a * wv;
        }
    }
#pragma unroll
    for (int q = 0; q < 4; ++q) acc[q] *= inv;
    if (out32) {
#pragma unroll
        for (int q = 0; q < 4; ++q)
            *(floatx4*)(out32 + (size_t)(m0 + m) * DD + fb + 32 * q) = acc[q];
    }
    if (outT) {
#pragma unroll
        for (int q = 0; q < 4; ++q)
#pragma unroll
            for (int e = 0; e < 4; ++e)
                outT[(size_t)(fb + 32 * q + e) * NN + m0 + m] = f32_bf16(acc[q][e]);
    }
}

// ---------------------------------------------------------------------------
extern "C" void kernel_launch(void* const* d_in, const int* in_sizes, int n_in,
                              void* d_out, int out_size, void* d_ws, size_t ws_size,
                              hipStream_t stream) {
    const float* adj = (const float*)d_in[0];
    const float* uni = (const float*)d_in[1];
    const float* sub = (const float*)d_in[2];
    const float* ws1 = (const float*)d_in[3];
    const float* wu1 = (const float*)d_in[4];
    float* out = (float*)d_out;

    const size_t SZ_A16 = (size_t)NN * NN * 2;       // 128 MiB each
    const size_t SZ_Y   = (size_t)8 * NN * DD * 4;   // 32 MiB
    const size_t SZ_F   = (size_t)NN * DD * 2;       // 2 MiB
    const size_t SZ_V   = (size_t)NN * 4;

    char* p = (char*)d_ws;
    unsigned short* A16  = (unsigned short*)p; p += SZ_A16;  // adj bf16 [u][s]
    unsigned short* AT16 = (unsigned short*)p; p += SZ_A16;  // adj^T bf16 [s][u]
    float* Yt = (float*)p; p += SZ_Y;                        // [8][128][8192]
    unsigned short* F[6];
    for (int i = 0; i < 6; ++i) { F[i] = (unsigned short*)p; p += SZ_F; }
    float* rsum = (float*)p; p += SZ_V;
    float* csum = (float*)p; p += SZ_V;

    hipMemsetAsync(rsum, 0, 2 * SZ_V, stream);   // rsum & csum contiguous
    convert_adj<<<dim3(32, 32), 512, 0, stream>>>(adj, AT16, A16, rsum, csum);
    convert_feat<<<dim3(128, 2), 256, 0, stream>>>(uni, F[0], NN, DD); // U0t
    convert_feat<<<dim3(128, 2), 256, 0, stream>>>(sub, F[1], NN, DD); // S0t

    unsigned short* Ut[3] = {F[0], F[3], F[5]};
    unsigned short* St[3] = {F[1], F[2], F[4]};

    for (int pass = 0; pass < 3; ++pass) {
        // G2: Ys = adjT @ U_prev, col-normalized, @ w_s1
        gemm_bigK<<<dim3(64, 8), 512, 0, stream>>>(AT16, Ut[pass], Yt);
        if (pass < 2)
            gemm_smallV<<<256, 256, 0, stream>>>(Yt, ws1, csum, nullptr, St[pass + 1]);
        else
            gemm_smallV<<<256, 256, 0, stream>>>(Yt, ws1, csum, out, nullptr);

        // G1: Yu = adj @ S_prev, row-normalized, @ w_u1
        gemm_bigK<<<dim3(64, 8), 512, 0, stream>>>(A16, St[pass], Yt);
        if (pass < 2)
            gemm_smallV<<<256, 256, 0, stream>>>(Yt, wu1, rsum, nullptr, Ut[pass + 1]);
        else
            gemm_smallV<<<256, 256, 0, stream>>>(Yt, wu1, rsum, out + (size_t)NN * DD, nullptr);
    }
}